// Round 1
// baseline (334.738 us; speedup 1.0000x reference)
//
#include <hip/hip_runtime.h>

#define N_IMG 4
#define C_CH  256
#define FH    100
#define FW    152
#define CHW   (C_CH * FH * FW)
#define OUT_PER_ROI (C_CH * 7 * 7)   // 12544
#define SCALE 0.0625f
#define ROW_BYTES (FW * C_CH * 4)    // 155648
#define CH_BYTES  (C_CH * 4)         // 1024
#define CPAD 260                     // padded channel stride (floats); 260*4=1040 B (16B-aligned rows)

typedef float f4 __attribute__((ext_vector_type(4)));

// ---------------- Kernel 1: NCHW -> NHWC transpose of features ----------------
// float4 loads along x (FW=152 % 4 == 0): 1 KB per wave-instr.
__global__ __launch_bounds__(256) void transpose_nchw_nhwc(
    const float* __restrict__ in, float* __restrict__ out) {
  const int x0 = blockIdx.x * 32;
  const int y  = blockIdx.y;
  const int b  = blockIdx.z;
  __shared__ float tile[32][C_CH + 1];   // [x][ch], +1 pad
  const int chl = threadIdx.x & 31;
  const int xq  = threadIdx.x >> 5;      // 0..7, covers x0+4*xq .. +3
  const int x   = x0 + xq * 4;
  const bool inb = (x < FW);             // FW%4==0 -> whole float4 in/out of bounds
  const float4* src4 = (const float4*)in;
#pragma unroll
  for (int cc = 0; cc < C_CH; cc += 32) {
    const int ch = cc + chl;
    float4 v = make_float4(0.f, 0.f, 0.f, 0.f);
    if (inb) v = src4[((size_t)b * C_CH + ch) * (FH * FW / 4) + y * (FW / 4) + (x >> 2)];
    tile[xq * 4 + 0][ch] = v.x;
    tile[xq * 4 + 1][ch] = v.y;
    tile[xq * 4 + 2][ch] = v.z;
    tile[xq * 4 + 3][ch] = v.w;
  }
  __syncthreads();
  const int ch = threadIdx.x;
  float* dst = out + (((size_t)b * FH + y) * FW) * C_CH + ch;
#pragma unroll
  for (int xi = 0; xi < 32; ++xi) {
    const int xx = x0 + xi;
    if (xx < FW) dst[(size_t)xx * C_CH] = tile[xi][ch];
  }
}

// ---------------- Kernel 2: RoIAlign + 2x2 overlapping avg pool (NHWC) --------
// 512 threads, one block per ROI.
// Phase 1: wave w (= sample row w, 8 waves) gathers its row's 8x4 bilinear
//   neighbors as float4 channel-groups (16 B/lane -> 1 KB/wave-instr; 32
//   independent loads in flight per thread). Samples staged in LDS
//   [64 pos][260 ch] (66.5 KB -> 2 blocks/CU with __launch_bounds__(512,4)).
// Phase 2: output-linear pooling. Each thread produces consecutive output
//   float4s (div-49 magic for c, p, j), 4 scalar LDS reads per element,
//   coalesced 1 KB/wave non-temporal stores (keep L2/L3 for the gathers).
__global__ __launch_bounds__(512, 4) void roialign_nhwc(
    const float* __restrict__ feat, const float* __restrict__ rois,
    const int* __restrict__ bids, float* __restrict__ out) {
  const int r  = blockIdx.x;
  const int cg = threadIdx.x & 63;       // channel group: channels 4*cg..4*cg+3
  const int i  = threadIdx.x >> 6;       // sample row 0..7 (wave-uniform)
  __shared__ float smp[64 * CPAD];       // 66,560 B

  const float x1 = rois[r * 4 + 0] * SCALE;
  const float y1 = rois[r * 4 + 1] * SCALE;
  const float x2 = rois[r * 4 + 2] * SCALE;
  const float y2 = rois[r * 4 + 3] * SCALE;
  const int   b  = bids[r];
  const float bw = fmaxf(x2 - x1 + 1.0f, 0.0f) * (1.0f / 7.0f);
  const float bh = fmaxf(y2 - y1 + 1.0f, 0.0f) * (1.0f / 7.0f);

  // Row weights (wave-uniform).
  const float h   = y1 + (float)i * bh;
  const float hsf = fminf(fmaxf(floorf(h), 0.0f), (float)(FH - 2));
  const float hr  = h - hsf;
  const float mh  = (h >= 0.0f && h < (float)FH) ? 1.0f : 0.0f;
  const float a0  = (1.0f - hr) * mh;
  const float a1  = hr * mh;

  const char* fbb  = (const char*)(feat + (size_t)b * CHW);
  const int   row0 = (int)hsf * ROW_BYTES + cg * 16;

  float* lbase = &smp[(i * 8) * CPAD + cg * 4];

#pragma unroll
  for (int j = 0; j < 8; ++j) {
    const float w   = x1 + (float)j * bw;
    const float wsf = fminf(fmaxf(floorf(w), 0.0f), (float)(FW - 2));
    const float wr  = w - wsf;
    const float mw  = (w >= 0.0f && w < (float)FW) ? 1.0f : 0.0f;
    const float q0  = (1.0f - wr) * mw;
    const float q1  = wr * mw;
    const int   o0  = row0 + (int)wsf * CH_BYTES;
    const f4 g00 = *(const f4*)(fbb + o0);
    const f4 g01 = *(const f4*)(fbb + o0 + CH_BYTES);
    const f4 g10 = *(const f4*)(fbb + o0 + ROW_BYTES);
    const f4 g11 = *(const f4*)(fbb + o0 + ROW_BYTES + CH_BYTES);
    const f4 s = (g00 * q0 + g01 * q1) * a0 + (g10 * q0 + g11 * q1) * a1;
    *(f4*)(lbase + j * CPAD) = s;
  }

  __syncthreads();

  // Phase 2: pooled writeback, output-linear (perfectly coalesced).
  f4* dst = (f4*)(out + (size_t)r * OUT_PER_ROI);
  const int g0 = (int)threadIdx.x * 4;
  int c   = (g0 * 669) >> 15;          // exact g/49 for g < 2048
  int rem = g0 - c * 49;
#pragma unroll
  for (int k = 0; k < 7; ++k) {
    const int idx = (int)threadIdx.x + k * 512;
    if (idx < (OUT_PER_ROI / 4)) {
      f4 v;
      int cc = c, rr = rem;
#pragma unroll
      for (int e = 0; e < 4; ++e) {
        const int p    = (rr * 37) >> 8;   // exact rr/7 for rr < 49
        const int j    = rr - p * 7;
        const int base = (p * 8 + j) * CPAD + cc;
        v[e] = (smp[base] + smp[base + CPAD] +
                smp[base + 8 * CPAD] + smp[base + 9 * CPAD]) * 0.25f;
        if (++rr == 49) { rr = 0; ++cc; }
      }
      __builtin_nontemporal_store(v, dst + idx);
    }
    rem += 39; c += 41;                 // advance by 2048 outputs
    if (rem >= 49) { rem -= 49; ++c; }
  }
}

// ---------------- Host launch ----------------
extern "C" void kernel_launch(void* const* d_in, const int* in_sizes, int n_in,
                              void* d_out, int out_size, void* d_ws, size_t ws_size,
                              hipStream_t stream) {
  (void)n_in; (void)out_size; (void)ws_size;
  const float* features = (const float*)d_in[0];
  const float* rois     = (const float*)d_in[1];
  const int*   bids     = (const int*)d_in[2];
  float* out = (float*)d_out;
  const int R = in_sizes[1] / 4;  // 4000

  float* nhwc = (float*)d_ws;     // 62.3 MB needed; harness ws is ample
  dim3 tgrid((FW + 31) / 32, FH, N_IMG);  // (5, 100, 4)
  transpose_nchw_nhwc<<<tgrid, 256, 0, stream>>>(features, nhwc);
  roialign_nhwc<<<R, 512, 0, stream>>>(nhwc, rois, bids, out);
}

// Round 2
// 296.577 us; speedup vs baseline: 1.1287x; 1.1287x over previous
//
#include <hip/hip_runtime.h>

#define N_IMG 4
#define C_CH  256
#define FH    100
#define FW    152
#define CHW   (C_CH * FH * FW)
#define OUT_PER_ROI (C_CH * 7 * 7)   // 12544
#define SCALE 0.0625f
#define ROW_BYTES (FW * C_CH * 4)    // 155648
#define CH_BYTES  (C_CH * 4)         // 1024
#define CPAD 260                     // padded channel stride (floats); 1040 B (16B-aligned rows)

typedef float f4 __attribute__((ext_vector_type(4)));

// ---------------- Kernel 0: bucket ROIs by (image, 8x8 spatial cell) ----------
// Single block counting sort of R indices; order[] is the processing order.
// Within-bucket order is nondeterministic (LDS atomics) — harmless: each ROI's
// output slot is fixed by its original index.
__global__ __launch_bounds__(256) void bin_rois(
    const float* __restrict__ rois, const int* __restrict__ bids, int R,
    int* __restrict__ order) {
  __shared__ int hist[256];
  __shared__ int base[256];
  for (int k = threadIdx.x; k < 256; k += 256) hist[k] = 0;
  __syncthreads();
  for (int r = threadIdx.x; r < R; r += 256) {
    const float cx = (rois[r * 4 + 0] + rois[r * 4 + 2]) * 0.5f * SCALE;
    const float cy = (rois[r * 4 + 1] + rois[r * 4 + 3]) * 0.5f * SCALE;
    int xb = (int)(cx * (8.0f / FW)); xb = xb < 0 ? 0 : (xb > 7 ? 7 : xb);
    int yb = (int)(cy * (8.0f / FH)); yb = yb < 0 ? 0 : (yb > 7 ? 7 : yb);
    const int key = (bids[r] << 6) | (yb << 3) | xb;
    atomicAdd(&hist[key], 1);
  }
  __syncthreads();
  if (threadIdx.x == 0) {
    int s = 0;
    for (int k = 0; k < 256; ++k) { base[k] = s; s += hist[k]; }
  }
  __syncthreads();
  for (int r = threadIdx.x; r < R; r += 256) {
    const float cx = (rois[r * 4 + 0] + rois[r * 4 + 2]) * 0.5f * SCALE;
    const float cy = (rois[r * 4 + 1] + rois[r * 4 + 3]) * 0.5f * SCALE;
    int xb = (int)(cx * (8.0f / FW)); xb = xb < 0 ? 0 : (xb > 7 ? 7 : xb);
    int yb = (int)(cy * (8.0f / FH)); yb = yb < 0 ? 0 : (yb > 7 ? 7 : yb);
    const int key = (bids[r] << 6) | (yb << 3) | xb;
    const int pos = atomicAdd(&base[key], 1);
    order[pos] = r;
  }
}

// ---------------- Kernel 1: NCHW -> NHWC transpose of features ----------------
// float4 loads along x AND float4 writes along ch: 1 KB per wave-instr both ways.
__global__ __launch_bounds__(256) void transpose_nchw_nhwc(
    const float* __restrict__ in, float* __restrict__ out) {
  const int x0 = blockIdx.x * 32;
  const int y  = blockIdx.y;
  const int b  = blockIdx.z;
  __shared__ float tile[32][C_CH + 4];   // [x][ch], +4 pad keeps rows 16B-aligned
  const int chl = threadIdx.x & 31;
  const int xq  = threadIdx.x >> 5;      // 0..7, covers x0+4*xq .. +3
  const int x   = x0 + xq * 4;
  const bool inb = (x < FW);             // FW%4==0 -> whole float4 in/out of bounds
  const float4* src4 = (const float4*)in;
#pragma unroll
  for (int cc = 0; cc < C_CH; cc += 32) {
    const int ch = cc + chl;
    float4 v = make_float4(0.f, 0.f, 0.f, 0.f);
    if (inb) v = src4[((size_t)b * C_CH + ch) * (FH * FW / 4) + y * (FW / 4) + (x >> 2)];
    tile[xq * 4 + 0][ch] = v.x;
    tile[xq * 4 + 1][ch] = v.y;
    tile[xq * 4 + 2][ch] = v.z;
    tile[xq * 4 + 3][ch] = v.w;
  }
  __syncthreads();
  const int chg = threadIdx.x & 63;      // channel group (4 ch)
  const int xs  = threadIdx.x >> 6;      // 0..3
  float* dstB = out + (((size_t)b * FH + y) * FW) * C_CH;
#pragma unroll
  for (int xi = 0; xi < 32; xi += 4) {
    const int xx = x0 + xi + xs;
    if (xx < FW) {
      const f4 v = *(const f4*)&tile[xi + xs][chg * 4];
      *(f4*)(dstB + (size_t)xx * C_CH + chg * 4) = v;
    }
  }
}

// ---------------- Kernel 2: RoIAlign + 2x2 overlapping avg pool (NHWC) --------
// 512 threads, one block per ROI. Blocks consume ROIs via order[] with a
// bijective XCD-chunk swizzle: XCD k gets sorted ranks [k*R/8, (k+1)*R/8) —
// spatially-adjacent same-image ROIs — so concurrent blocks on an XCD share
// feature rows in the 4 MB per-XCD L2 (the gather stream is 16x-amplified
// re-reads of a 62 MB array; locality decides L2 vs L3 service).
__global__ __launch_bounds__(512, 4) void roialign_nhwc(
    const float* __restrict__ feat, const float* __restrict__ rois,
    const int* __restrict__ bids, const int* __restrict__ order,
    int R, float* __restrict__ out) {
  const int g  = blockIdx.x;
  const int r  = order[((R & 7) == 0) ? ((g & 7) * (R >> 3) + (g >> 3)) : g];
  const int cg = threadIdx.x & 63;       // channel group: channels 4*cg..4*cg+3
  const int i  = threadIdx.x >> 6;       // sample row 0..7 (wave-uniform)
  __shared__ float smp[64 * CPAD];       // 66,560 B -> 2 blocks/CU

  const float x1 = rois[r * 4 + 0] * SCALE;
  const float y1 = rois[r * 4 + 1] * SCALE;
  const float x2 = rois[r * 4 + 2] * SCALE;
  const float y2 = rois[r * 4 + 3] * SCALE;
  const int   b  = bids[r];
  const float bw = fmaxf(x2 - x1 + 1.0f, 0.0f) * (1.0f / 7.0f);
  const float bh = fmaxf(y2 - y1 + 1.0f, 0.0f) * (1.0f / 7.0f);

  // Row weights (wave-uniform).
  const float h   = y1 + (float)i * bh;
  const float hsf = fminf(fmaxf(floorf(h), 0.0f), (float)(FH - 2));
  const float hr  = h - hsf;
  const float mh  = (h >= 0.0f && h < (float)FH) ? 1.0f : 0.0f;
  const float a0  = (1.0f - hr) * mh;
  const float a1  = hr * mh;

  const char* fbb  = (const char*)(feat + (size_t)b * CHW);
  const int   row0 = (int)hsf * ROW_BYTES + cg * 16;

  float* lbase = &smp[(i * 8) * CPAD + cg * 4];

#pragma unroll
  for (int j = 0; j < 8; ++j) {
    const float w   = x1 + (float)j * bw;
    const float wsf = fminf(fmaxf(floorf(w), 0.0f), (float)(FW - 2));
    const float wr  = w - wsf;
    const float mw  = (w >= 0.0f && w < (float)FW) ? 1.0f : 0.0f;
    const float q0  = (1.0f - wr) * mw;
    const float q1  = wr * mw;
    const int   o0  = row0 + (int)wsf * CH_BYTES;
    const f4 g00 = *(const f4*)(fbb + o0);
    const f4 g01 = *(const f4*)(fbb + o0 + CH_BYTES);
    const f4 g10 = *(const f4*)(fbb + o0 + ROW_BYTES);
    const f4 g11 = *(const f4*)(fbb + o0 + ROW_BYTES + CH_BYTES);
    const f4 s = (g00 * q0 + g01 * q1) * a0 + (g10 * q0 + g11 * q1) * a1;
    *(f4*)(lbase + j * CPAD) = s;
  }

  __syncthreads();

  // Phase 2: pooled writeback, output-linear (perfectly coalesced).
  f4* dst = (f4*)(out + (size_t)r * OUT_PER_ROI);
  const int g0 = (int)threadIdx.x * 4;
  int c   = (g0 * 669) >> 15;          // exact g/49 for g < 2048
  int rem = g0 - c * 49;
#pragma unroll
  for (int k = 0; k < 7; ++k) {
    const int idx = (int)threadIdx.x + k * 512;
    if (idx < (OUT_PER_ROI / 4)) {
      f4 v;
      int cc = c, rr = rem;
#pragma unroll
      for (int e = 0; e < 4; ++e) {
        const int p    = (rr * 37) >> 8;   // exact rr/7 for rr < 49
        const int j    = rr - p * 7;
        const int base = (p * 8 + j) * CPAD + cc;
        v[e] = (smp[base] + smp[base + CPAD] +
                smp[base + 8 * CPAD] + smp[base + 9 * CPAD]) * 0.25f;
        if (++rr == 49) { rr = 0; ++cc; }
      }
      __builtin_nontemporal_store(v, dst + idx);
    }
    rem += 39; c += 41;                 // advance by 2048 outputs
    if (rem >= 49) { rem -= 49; ++c; }
  }
}

// ---------------- Host launch ----------------
extern "C" void kernel_launch(void* const* d_in, const int* in_sizes, int n_in,
                              void* d_out, int out_size, void* d_ws, size_t ws_size,
                              hipStream_t stream) {
  (void)n_in; (void)out_size; (void)ws_size;
  const float* features = (const float*)d_in[0];
  const float* rois     = (const float*)d_in[1];
  const int*   bids     = (const int*)d_in[2];
  float* out = (float*)d_out;
  const int R = in_sizes[1] / 4;  // 4000

  float* nhwc  = (float*)d_ws;                       // 62.3 MB
  int*   order = (int*)((char*)d_ws + (64u << 20));  // 16 KB at +64 MB

  bin_rois<<<1, 256, 0, stream>>>(rois, bids, R, order);
  dim3 tgrid((FW + 31) / 32, FH, N_IMG);  // (5, 100, 4)
  transpose_nchw_nhwc<<<tgrid, 256, 0, stream>>>(features, nhwc);
  roialign_nhwc<<<R, 512, 0, stream>>>(nhwc, rois, bids, order, R, out);
}

// Round 5
// 285.830 us; speedup vs baseline: 1.1711x; 1.0376x over previous
//
#include <hip/hip_runtime.h>

#define N_IMG 4
#define C_CH  256
#define FH    100
#define FW    152
#define CHW   (C_CH * FH * FW)
#define OUT_PER_ROI (C_CH * 7 * 7)   // 12544
#define SCALE 0.0625f
#define H_ROW_BYTES (FW * C_CH * 2)  // 77824  (f16 NHWC feature row)
#define H_CH_BYTES  (C_CH * 2)       // 512    (one (y,x) cell, f16)
#define CPAD 260                     // padded channel stride (floats); 1040 B (16B-aligned rows)

typedef float    f4 __attribute__((ext_vector_type(4)));
typedef _Float16 h4 __attribute__((ext_vector_type(4)));

// ---------------- Kernel 0: bucket ROIs by (image, 8x8 spatial cell) ----------
// Single block counting sort of R indices; order[] is the processing order.
__global__ __launch_bounds__(256) void bin_rois(
    const float* __restrict__ rois, const int* __restrict__ bids, int R,
    int* __restrict__ order) {
  __shared__ int hist[256];
  __shared__ int base[256];
  for (int k = threadIdx.x; k < 256; k += 256) hist[k] = 0;
  __syncthreads();
  for (int r = threadIdx.x; r < R; r += 256) {
    const float cx = (rois[r * 4 + 0] + rois[r * 4 + 2]) * 0.5f * SCALE;
    const float cy = (rois[r * 4 + 1] + rois[r * 4 + 3]) * 0.5f * SCALE;
    int xb = (int)(cx * (8.0f / FW)); xb = xb < 0 ? 0 : (xb > 7 ? 7 : xb);
    int yb = (int)(cy * (8.0f / FH)); yb = yb < 0 ? 0 : (yb > 7 ? 7 : yb);
    const int key = (bids[r] << 6) | (yb << 3) | xb;
    atomicAdd(&hist[key], 1);
  }
  __syncthreads();
  if (threadIdx.x == 0) {
    int s = 0;
    for (int k = 0; k < 256; ++k) { base[k] = s; s += hist[k]; }
  }
  __syncthreads();
  for (int r = threadIdx.x; r < R; r += 256) {
    const float cx = (rois[r * 4 + 0] + rois[r * 4 + 2]) * 0.5f * SCALE;
    const float cy = (rois[r * 4 + 1] + rois[r * 4 + 3]) * 0.5f * SCALE;
    int xb = (int)(cx * (8.0f / FW)); xb = xb < 0 ? 0 : (xb > 7 ? 7 : xb);
    int yb = (int)(cy * (8.0f / FH)); yb = yb < 0 ? 0 : (yb > 7 ? 7 : yb);
    const int key = (bids[r] << 6) | (yb << 3) | xb;
    const int pos = atomicAdd(&base[key], 1);
    order[pos] = r;
  }
}

// ---------------- Kernel 1: NCHW f32 -> NHWC f16 transpose of features -------
// float4 loads along x; h4 (8 B) writes along ch. Halves the gather-side
// bytes AND the per-XCD L2 footprint (half-image chunk 7.8 -> 3.9 MB: fits).
__global__ __launch_bounds__(256) void transpose_nchw_nhwc(
    const float* __restrict__ in, _Float16* __restrict__ out) {
  const int x0 = blockIdx.x * 32;
  const int y  = blockIdx.y;
  const int b  = blockIdx.z;
  __shared__ float tile[32][C_CH + 4];   // [x][ch], +4 pad keeps rows 16B-aligned
  const int chl = threadIdx.x & 31;
  const int xq  = threadIdx.x >> 5;      // 0..7, covers x0+4*xq .. +3
  const int x   = x0 + xq * 4;
  const bool inb = (x < FW);             // FW%4==0 -> whole float4 in/out of bounds
  const float4* src4 = (const float4*)in;
#pragma unroll
  for (int cc = 0; cc < C_CH; cc += 32) {
    const int ch = cc + chl;
    float4 v = make_float4(0.f, 0.f, 0.f, 0.f);
    if (inb) v = src4[((size_t)b * C_CH + ch) * (FH * FW / 4) + y * (FW / 4) + (x >> 2)];
    tile[xq * 4 + 0][ch] = v.x;
    tile[xq * 4 + 1][ch] = v.y;
    tile[xq * 4 + 2][ch] = v.z;
    tile[xq * 4 + 3][ch] = v.w;
  }
  __syncthreads();
  const int chg = threadIdx.x & 63;      // channel group (4 ch)
  const int xs  = threadIdx.x >> 6;      // 0..3
  _Float16* dstB = out + (((size_t)b * FH + y) * FW) * C_CH;
#pragma unroll
  for (int xi = 0; xi < 32; xi += 4) {
    const int xx = x0 + xi + xs;
    if (xx < FW) {
      const f4 v = *(const f4*)&tile[xi + xs][chg * 4];
      h4 hv;
      hv[0] = (_Float16)v[0]; hv[1] = (_Float16)v[1];
      hv[2] = (_Float16)v[2]; hv[3] = (_Float16)v[3];
      *(h4*)(dstB + (size_t)xx * C_CH + chg * 4) = hv;
    }
  }
}

// ---------------- Kernel 2: RoIAlign + 2x2 overlapping avg pool (NHWC f16) ---
// 512 threads, one block per ROI, ROIs consumed via order[] + bijective XCD
// chunk swizzle (locality -> per-XCD L2). Gathers are h4 (8 B/lane; one cell's
// 512 B = exactly one wave-instr). All interpolation math in f32; only the
// staged feature values are f16-quantized.
__global__ __launch_bounds__(512, 4) void roialign_nhwc(
    const _Float16* __restrict__ feat, const float* __restrict__ rois,
    const int* __restrict__ bids, const int* __restrict__ order,
    int R, float* __restrict__ out) {
  const int g  = blockIdx.x;
  const int r  = order[((R & 7) == 0) ? ((g & 7) * (R >> 3) + (g >> 3)) : g];
  const int cg = threadIdx.x & 63;       // channel group: channels 4*cg..4*cg+3
  const int i  = threadIdx.x >> 6;       // sample row 0..7 (wave-uniform)
  __shared__ float smp[64 * CPAD];       // 66,560 B -> 2 blocks/CU

  const float x1 = rois[r * 4 + 0] * SCALE;
  const float y1 = rois[r * 4 + 1] * SCALE;
  const float x2 = rois[r * 4 + 2] * SCALE;
  const float y2 = rois[r * 4 + 3] * SCALE;
  const int   b  = bids[r];
  const float bw = fmaxf(x2 - x1 + 1.0f, 0.0f) * (1.0f / 7.0f);
  const float bh = fmaxf(y2 - y1 + 1.0f, 0.0f) * (1.0f / 7.0f);

  // Row weights (wave-uniform).
  const float h   = y1 + (float)i * bh;
  const float hsf = fminf(fmaxf(floorf(h), 0.0f), (float)(FH - 2));
  const float hr  = h - hsf;
  const float mh  = (h >= 0.0f && h < (float)FH) ? 1.0f : 0.0f;
  const float a0  = (1.0f - hr) * mh;
  const float a1  = hr * mh;

  const char* fbb  = (const char*)feat + (size_t)b * CHW * 2;
  const int   row0 = (int)hsf * H_ROW_BYTES + cg * 8;

  float* lbase = &smp[(i * 8) * CPAD + cg * 4];

#pragma unroll
  for (int j = 0; j < 8; ++j) {
    const float w   = x1 + (float)j * bw;
    const float wsf = fminf(fmaxf(floorf(w), 0.0f), (float)(FW - 2));
    const float wr  = w - wsf;
    const float mw  = (w >= 0.0f && w < (float)FW) ? 1.0f : 0.0f;
    const float q0  = (1.0f - wr) * mw;
    const float q1  = wr * mw;
    const int   o0  = row0 + (int)wsf * H_CH_BYTES;
    const h4 h00 = *(const h4*)(fbb + o0);
    const h4 h01 = *(const h4*)(fbb + o0 + H_CH_BYTES);
    const h4 h10 = *(const h4*)(fbb + o0 + H_ROW_BYTES);
    const h4 h11 = *(const h4*)(fbb + o0 + H_ROW_BYTES + H_CH_BYTES);
    const f4 g00 = __builtin_convertvector(h00, f4);
    const f4 g01 = __builtin_convertvector(h01, f4);
    const f4 g10 = __builtin_convertvector(h10, f4);
    const f4 g11 = __builtin_convertvector(h11, f4);
    const f4 s = (g00 * q0 + g01 * q1) * a0 + (g10 * q0 + g11 * q1) * a1;
    *(f4*)(lbase + j * CPAD) = s;
  }

  __syncthreads();

  // Phase 2: pooled writeback, output-linear (perfectly coalesced).
  f4* dst = (f4*)(out + (size_t)r * OUT_PER_ROI);
  const int g0 = (int)threadIdx.x * 4;
  int c   = (g0 * 669) >> 15;          // exact g/49 for g < 2048
  int rem = g0 - c * 49;
#pragma unroll
  for (int k = 0; k < 7; ++k) {
    const int idx = (int)threadIdx.x + k * 512;
    if (idx < (OUT_PER_ROI / 4)) {
      f4 v;
      int cc = c, rr = rem;
#pragma unroll
      for (int e = 0; e < 4; ++e) {
        const int p    = (rr * 37) >> 8;   // exact rr/7 for rr < 49
        const int j    = rr - p * 7;
        const int base = (p * 8 + j) * CPAD + cc;
        v[e] = (smp[base] + smp[base + CPAD] +
                smp[base + 8 * CPAD] + smp[base + 9 * CPAD]) * 0.25f;
        if (++rr == 49) { rr = 0; ++cc; }
      }
      __builtin_nontemporal_store(v, dst + idx);
    }
    rem += 39; c += 41;                 // advance by 2048 outputs
    if (rem >= 49) { rem -= 49; ++c; }
  }
}

// ---------------- Host launch ----------------
extern "C" void kernel_launch(void* const* d_in, const int* in_sizes, int n_in,
                              void* d_out, int out_size, void* d_ws, size_t ws_size,
                              hipStream_t stream) {
  (void)n_in; (void)out_size; (void)ws_size;
  const float* features = (const float*)d_in[0];
  const float* rois     = (const float*)d_in[1];
  const int*   bids     = (const int*)d_in[2];
  float* out = (float*)d_out;
  const int R = in_sizes[1] / 4;  // 4000

  _Float16* nhwc  = (_Float16*)d_ws;                 // 31.1 MB (f16 NHWC)
  int*      order = (int*)((char*)d_ws + (64u << 20));  // 16 KB at +64 MB

  bin_rois<<<1, 256, 0, stream>>>(rois, bids, R, order);
  dim3 tgrid((FW + 31) / 32, FH, N_IMG);  // (5, 100, 4)
  transpose_nchw_nhwc<<<tgrid, 256, 0, stream>>>(features, nhwc);
  roialign_nhwc<<<R, 512, 0, stream>>>(nhwc, rois, bids, order, R, out);
}